// Round 2
// baseline (9453.259 us; speedup 1.0000x reference)
//
#include <hip/hip_runtime.h>

#define HID   1024
#define TLEN  512
#define VOC   128
#define NBLK  256         // = #CUs; 1 block/CU -> all co-resident
#define NW    32          // worker team: all 32 blocks of the winner XCD
#define LDSK  1032        // padded LDS row stride
#define HBUF  (64 * HID)  // one h buffer (elements)

typedef __bf16 bf16_t;
typedef __attribute__((ext_vector_type(8))) __bf16 bf16x8;
typedef __attribute__((ext_vector_type(4))) float  f32x4;

__device__ __forceinline__ float sigmoid_fast(float x) {
  return 1.0f / (1.0f + __expf(-x));
}
__device__ __forceinline__ float tanh_fast(float x) {
  float e = __expf(-2.0f * x);
  return (1.0f - e) / (1.0f + e);
}

union PairU { bf16_t b[2]; unsigned u; };

// L1-only invalidate: subsequent plain loads re-read the (same-XCD) L2.
__device__ __forceinline__ void l1_inv() {
  asm volatile("buffer_inv" ::: "memory");
}

__device__ __forceinline__ bf16x8 ldw(const bf16_t* p) {
  return *reinterpret_cast<const bf16x8*>(p);
}

// Per-wave busy poll of the 32 per-producer epoch words (one 128B L2 line).
// No s_sleep (keep the SQ busy / clocks up), no barrier (publish has one).
// The buffer_inv in the final successful iteration also freshens all data
// lines this CU holds, so the h/rh loads that follow need no extra inv.
__device__ __forceinline__ void wait_flags(const unsigned* f, unsigned tgt) {
  const volatile unsigned* p =
      (const volatile unsigned*)(f + (threadIdx.x & 31));
  for (;;) {
    l1_inv();
    unsigned v = *p;
    if (__all((int)(v - tgt) >= 0)) break;   // wrap-safe compare
  }
}

// publish: __syncthreads drains this block's write-through data stores into
// L2 (vmcnt(0) before s_barrier), then one plain store of the epoch value.
__device__ __forceinline__ void publish(unsigned* fw, unsigned v) {
  __syncthreads();
  if (threadIdx.x == 0) *(volatile unsigned*)fw = v;
}

#define MFMA(a, b, c) __builtin_amdgcn_mfma_f32_16x16x32_bf16((a), (b), (c), 0, 0, 0)

__global__ void __launch_bounds__(256, 1)
gru_team(const int* __restrict__ X,
         const float* __restrict__ Wr_x, const float* __restrict__ Wr_h, const float* __restrict__ b_r,
         const float* __restrict__ Wz_x, const float* __restrict__ Wz_h, const float* __restrict__ b_z,
         const float* __restrict__ Wh_x, const float* __restrict__ Wh_h, const float* __restrict__ b_h,
         const float* __restrict__ W_o,  const float* __restrict__ b_o,
         float* __restrict__ out,
         bf16_t* __restrict__ hring, bf16_t* __restrict__ rh_bf,
         bf16_t* __restrict__ wz_bf, bf16_t* __restrict__ wo_bf,
         unsigned* __restrict__ flags)
{
  __shared__ __align__(16) bf16_t Wbuf[2 * 32 * LDSK];  // Wr + Wh slices, 129KB
  __shared__ __align__(16) float  Obuf[8][16][16];      // out staging, 8KB
  __shared__ int s_role;

  unsigned* fH     = flags;        // words [0,32): h-epoch per producer block
  unsigned* fR     = flags + 32;   // words [32,64): rh-epoch per producer
  unsigned* cnt    = flags + 128;  // per-XCD claim counters (MALL atomics)
  unsigned* winner = flags + 160;  // 0 = unset, else xcd+1
  unsigned* ready  = flags + 168;  // one-time team barrier (MALL atomics)
  unsigned* done   = flags + 172;  // spinners exit when nonzero (MALL)

  const int tid  = threadIdx.x;
  const int lane = tid & 63;
  const int wv   = tid >> 6;
  const int n16  = lane & 15;
  const int q    = lane >> 4;
  const int aoff = (wv * 16 + n16) * HID + q * 8;

  int bi[4];
#pragma unroll
  for (int i = 0; i < 4; ++i) bi[i] = wv * 16 + q * 4 + i;

  // ---------- self-organize: first XCD to seat 32 blocks = worker team ------
  if (tid == 0) {
    unsigned xcc;
    asm volatile("s_getreg_b32 %0, hwreg(HW_REG_XCC_ID)" : "=s"(xcc));
    xcc &= 7u;
    unsigned idx = __hip_atomic_fetch_add(&cnt[xcc], 1u, __ATOMIC_RELAXED, __HIP_MEMORY_SCOPE_AGENT);
    if (idx == NW - 1) {
      unsigned exp = 0u;
      __hip_atomic_compare_exchange_strong(winner, &exp, xcc + 1u,
          __ATOMIC_RELAXED, __ATOMIC_RELAXED, __HIP_MEMORY_SCOPE_AGENT);
    }
    unsigned w;
    do {
      w = __hip_atomic_load(winner, __ATOMIC_RELAXED, __HIP_MEMORY_SCOPE_AGENT);
      __builtin_amdgcn_s_sleep(1);
    } while (w == 0u);
    s_role = (xcc == w - 1u && idx < NW) ? (int)idx : -1;
  }
  __syncthreads();
  const int role = s_role;

  if (role < 0) {
    // ============ clock-keepers: hold the SMU at high DPM ===================
    // 4 independent FMA chains -> ~full VALU issue rate on 224 CUs. Exit when
    // the worker team publishes `done` (agent-scope load reads the MALL).
    __shared__ volatile int sdone;
    if (tid == 0) sdone = 0;
    __syncthreads();
    float a0 = 1.0f + (float)tid, a1 = 1.1f, a2 = 1.2f, a3 = 1.3f;
    const float m = 1.0000001f, c = 1e-7f;
    while (!sdone) {
      for (int it = 0; it < 1024; ++it) {
        a0 = __builtin_fmaf(a0, m, c);
        a1 = __builtin_fmaf(a1, m, c);
        a2 = __builtin_fmaf(a2, m, c);
        a3 = __builtin_fmaf(a3, m, c);
      }
      if (tid == 0 &&
          __hip_atomic_load(done, __ATOMIC_RELAXED, __HIP_MEMORY_SCOPE_AGENT) != 0u)
        sdone = 1;
    }
    asm volatile("" :: "v"(a0), "v"(a1), "v"(a2), "v"(a3));
    return;
  }

  const int s  = role;
  const int c0 = s * 32;

  // Reset my epoch words in this XCD's L2 (replay-safety; ordered before any
  // poll by the ready-barrier below).
  if (tid == 0) {
    *(volatile unsigned*)&fH[s] = 0u;
    *(volatile unsigned*)&fR[s] = 0u;
  }

  // ---------- staging: Wr/Wh -> LDS, Wz slice -> L2, W_o slice -> L2 --------
  for (int idx = tid; idx < 32 * HID; idx += 256) {
    int n = idx & 31, k = idx >> 5;
    int r = (n & 1) * 16 + (n >> 1);
    Wbuf[r * LDSK + k]             = (bf16_t)Wr_h[k * HID + c0 + n];
    Wbuf[32 * LDSK + r * LDSK + k] = (bf16_t)Wh_h[k * HID + c0 + n];
  }
  bf16_t* wzs = wz_bf + s * (32 * 1024);
  for (int idx = tid; idx < 32 * HID; idx += 256) {
    int n = idx & 31, k = idx >> 5;
    int r = (n & 1) * 16 + (n >> 1);
    wzs[r * 1024 + k] = (bf16_t)Wz_h[k * HID + c0 + n];
  }
  if (s < 8) {
    bf16_t* wos = wo_bf + s * (16 * 1024);
    for (int idx = tid; idx < 16 * HID; idx += 256) {
      int n = idx & 15, k = idx >> 4;
      wos[n * 1024 + k] = (bf16_t)W_o[k * VOC + s * 16 + n];
    }
  }
  const int j0 = c0 + 2 * n16;
#pragma unroll
  for (int i = 0; i < 4; ++i) {
    PairU zz; zz.b[0] = (bf16_t)0.f; zz.b[1] = (bf16_t)0.f;
    *reinterpret_cast<PairU*>(hring + bi[i] * HID + j0) = zz;   // h_0 = 0
  }
  __syncthreads();   // drains flag-zeroes + staging + h0

  // one-time team-wide MALL barrier
  if (tid == 0) {
    __hip_atomic_fetch_add(ready, 1u, __ATOMIC_RELAXED, __HIP_MEMORY_SCOPE_AGENT);
    while (__hip_atomic_load(ready, __ATOMIC_RELAXED, __HIP_MEMORY_SCOPE_AGENT) < NW)
      __builtin_amdgcn_s_sleep(1);
  }
  __syncthreads();
  if (tid == 0) *(volatile unsigned*)&fH[s] = 1u;   // h slot 0 ready

  // ---------- per-step constants ----------
  const float br0 = b_r[j0], br1 = b_r[j0 + 1];
  const float bz0 = b_z[j0], bz1 = b_z[j0 + 1];
  const float bh0 = b_h[j0], bh1 = b_h[j0 + 1];
  const bf16_t* wr0 = &Wbuf[n16 * LDSK + q * 8];
  const bf16_t* wr1 = &Wbuf[(16 + n16) * LDSK + q * 8];
  const bf16_t* wh0 = &Wbuf[32 * LDSK + n16 * LDSK + q * 8];
  const bf16_t* wh1 = &Wbuf[32 * LDSK + (16 + n16) * LDSK + q * 8];
  const bf16_t* wz0 = wzs + n16 * 1024 + q * 8;
  const bf16_t* wz1 = wzs + (16 + n16) * 1024 + q * 8;
  const bf16_t* rhrow = rh_bf + aoff;

  // out tile ownership: block s -> (row-tile rt, vocab-tile vt); wave rt holds
  // exactly rows rt*16..rt*16+15 of h in its areg.
  const int rt = s >> 3, vt = s & 7;
  const bool outw = (wv == rt);
  const bf16_t* wop = wo_bf + vt * (16 * 1024) + n16 * 1024 + q * 8;
  const float bo = b_o[vt * 16 + n16];

  f32x4 hm0 = {0.f,0.f,0.f,0.f}, hm1 = {0.f,0.f,0.f,0.f};  // fp32 h master

  for (int t = 0; t < TLEN; ++t) {
    // x-gather prefetch (hides under the hop-A poll)
    float gr0[4], gr1[4], gz0[4], gz1[4], gh0[4], gh1[4];
#pragma unroll
    for (int i = 0; i < 4; ++i) {
      int xb = X[bi[i] * TLEN + t];
      gr0[i] = Wr_x[xb * HID + j0]; gr1[i] = Wr_x[xb * HID + j0 + 1];
      gz0[i] = Wz_x[xb * HID + j0]; gz1[i] = Wz_x[xb * HID + j0 + 1];
      gh0[i] = Wh_x[xb * HID + j0]; gh1[i] = Wh_x[xb * HID + j0 + 1];
    }

    // ---- hop A: h_t ready ----
    wait_flags(fH, (unsigned)(t + 1));
    const bf16_t* hrow = hring + (t & 1) * HBUF + aoff;
    bf16x8 areg[32];
#pragma unroll
    for (int kk = 0; kk < 32; ++kk) areg[kk] = ldw(hrow + kk * 32);

    // ---- r phase (critical; 4 independent MFMA chains) ----
    f32x4 aR0 = {0.f,0.f,0.f,0.f}, aR1 = {0.f,0.f,0.f,0.f};
    f32x4 bR0 = {0.f,0.f,0.f,0.f}, bR1 = {0.f,0.f,0.f,0.f};
#pragma unroll
    for (int kk = 0; kk < 16; ++kk) {
      aR0 = MFMA(areg[kk],      ldw(wr0 + kk * 32),        aR0);
      aR1 = MFMA(areg[kk],      ldw(wr1 + kk * 32),        aR1);
      bR0 = MFMA(areg[kk + 16], ldw(wr0 + (kk + 16) * 32), bR0);
      bR1 = MFMA(areg[kk + 16], ldw(wr1 + (kk + 16) * 32), bR1);
    }
    aR0 += bR0; aR1 += bR1;
#pragma unroll
    for (int i = 0; i < 4; ++i) {
      float r0 = sigmoid_fast(aR0[i] + br0 + gr0[i]);
      float r1 = sigmoid_fast(aR1[i] + br1 + gr1[i]);
      PairU c;
      c.b[0] = (bf16_t)(r0 * hm0[i]);   // fp32 register master (== h_t)
      c.b[1] = (bf16_t)(r1 * hm1[i]);
      *reinterpret_cast<PairU*>(rh_bf + bi[i] * HID + j0) = c;  // local L2
    }
    publish(&fR[s], (unsigned)(t + 1));

    // ---- out[t-1] = h_t @ W_o (shadow; stores batched via LDS) ----
    if (outw && t) {
      f32x4 oa = {0.f,0.f,0.f,0.f}, ob2 = {0.f,0.f,0.f,0.f};
#pragma unroll
      for (int kk = 0; kk < 16; ++kk) {
        oa  = MFMA(areg[kk],      ldw(wop + kk * 32),        oa);
        ob2 = MFMA(areg[kk + 16], ldw(wop + (kk + 16) * 32), ob2);
      }
      oa += ob2;
      const int oi = (t - 1) & 7;
#pragma unroll
      for (int i = 0; i < 4; ++i) Obuf[oi][q * 4 + i][n16] = oa[i] + bo;
      if (oi == 7) {
        const int rb = t - 8;  // out rows rb..rb+7
#pragma unroll
        for (int k = 0; k < 8; ++k)
#pragma unroll
          for (int i = 0; i < 4; ++i)
            out[(bi[i] * TLEN + rb + k) * VOC + vt * 16 + n16] =
                Obuf[k][q * 4 + i][n16];
      }
    }

    // ---- z phase (shadow; reuses areg, streams wz from local L2) ----
    f32x4 aZ0 = {0.f,0.f,0.f,0.f}, aZ1 = {0.f,0.f,0.f,0.f};
    f32x4 bZ0 = {0.f,0.f,0.f,0.f}, bZ1 = {0.f,0.f,0.f,0.f};
#pragma unroll
    for (int kk = 0; kk < 16; ++kk) {
      aZ0 = MFMA(areg[kk],      ldw(wz0 + kk * 32),        aZ0);
      aZ1 = MFMA(areg[kk],      ldw(wz1 + kk * 32),        aZ1);
      bZ0 = MFMA(areg[kk + 16], ldw(wz0 + (kk + 16) * 32), bZ0);
      bZ1 = MFMA(areg[kk + 16], ldw(wz1 + (kk + 16) * 32), bZ1);
    }
    aZ0 += bZ0; aZ1 += bZ1;
    f32x4 z0, z1;
#pragma unroll
    for (int i = 0; i < 4; ++i) {
      z0[i] = sigmoid_fast(aZ0[i] + bz0 + gz0[i]);
      z1[i] = sigmoid_fast(aZ1[i] + bz1 + gz1[i]);
    }

    // ---- hop B: rh ready; h_tilde phase (critical) ----
    wait_flags(fR, (unsigned)(t + 1));
    bf16x8 breg[32];
#pragma unroll
    for (int kk = 0; kk < 32; ++kk) breg[kk] = ldw(rhrow + kk * 32);
    f32x4 aH0 = {0.f,0.f,0.f,0.f}, aH1 = {0.f,0.f,0.f,0.f};
    f32x4 bH0 = {0.f,0.f,0.f,0.f}, bH1 = {0.f,0.f,0.f,0.f};
#pragma unroll
    for (int kk = 0; kk < 16; ++kk) {
      aH0 = MFMA(breg[kk],      ldw(wh0 + kk * 32),        aH0);
      aH1 = MFMA(breg[kk],      ldw(wh1 + kk * 32),        aH1);
      bH0 = MFMA(breg[kk + 16], ldw(wh0 + (kk + 16) * 32), bH0);
      bH1 = MFMA(breg[kk + 16], ldw(wh1 + (kk + 16) * 32), bH1);
    }
    aH0 += bH0; aH1 += bH1;
    bf16_t* hnext = hring + ((t + 1) & 1) * HBUF;
#pragma unroll
    for (int i = 0; i < 4; ++i) {
      float ht0 = tanh_fast(aH0[i] + bh0 + gh0[i]);
      float ht1 = tanh_fast(aH1[i] + bh1 + gh1[i]);
      float hn0 = z0[i] * hm0[i] + (1.f - z0[i]) * ht0;
      float hn1 = z1[i] * hm1[i] + (1.f - z1[i]) * ht1;
      hm0[i] = hn0; hm1[i] = hn1;
      PairU c; c.b[0] = (bf16_t)hn0; c.b[1] = (bf16_t)hn1;
      *reinterpret_cast<PairU*>(hnext + bi[i] * HID + j0) = c;  // local L2
    }
    publish(&fH[s], (unsigned)(t + 2));
  }

  // ---- epilogue: out[TLEN-1] = h_TLEN @ W_o, flush rows 504..511 ----
  if (outw) {
    wait_flags(fH, (unsigned)(TLEN + 1));
    const bf16_t* hrow = hring + (TLEN & 1) * HBUF + aoff;
    bf16x8 areg[32];
#pragma unroll
    for (int kk = 0; kk < 32; ++kk) areg[kk] = ldw(hrow + kk * 32);
    f32x4 oa = {0.f,0.f,0.f,0.f}, ob2 = {0.f,0.f,0.f,0.f};
#pragma unroll
    for (int kk = 0; kk < 16; ++kk) {
      oa  = MFMA(areg[kk],      ldw(wop + kk * 32),        oa);
      ob2 = MFMA(areg[kk + 16], ldw(wop + (kk + 16) * 32), ob2);
    }
    oa += ob2;
#pragma unroll
    for (int i = 0; i < 4; ++i) Obuf[7][q * 4 + i][n16] = oa[i] + bo;
#pragma unroll
    for (int k = 0; k < 8; ++k)
#pragma unroll
      for (int i = 0; i < 4; ++i)
        out[(bi[i] * TLEN + 504 + k) * VOC + vt * 16 + n16] =
            Obuf[k][q * 4 + i][n16];
  }

  if (s == 0 && tid == 0)
    __hip_atomic_store(done, 1u, __ATOMIC_RELAXED, __HIP_MEMORY_SCOPE_AGENT);

  // write back/order dirty state for the next replay
  __builtin_amdgcn_fence(__ATOMIC_RELEASE, "agent");
}

extern "C" void kernel_launch(void* const* d_in, const int* in_sizes, int n_in,
                              void* d_out, int out_size, void* d_ws, size_t ws_size,
                              hipStream_t stream) {
  const int*   X    = (const int*)d_in[0];
  const float* Wr_x = (const float*)d_in[1];
  const float* Wr_h = (const float*)d_in[2];
  const float* b_r  = (const float*)d_in[3];
  const float* Wz_x = (const float*)d_in[4];
  const float* Wz_h = (const float*)d_in[5];
  const float* b_z  = (const float*)d_in[6];
  const float* Wh_x = (const float*)d_in[7];
  const float* Wh_h = (const float*)d_in[8];
  const float* b_h  = (const float*)d_in[9];
  const float* W_o  = (const float*)d_in[10];
  const float* b_o  = (const float*)d_in[11];

  char* ws = (char*)d_ws;
  // layout: [flags 4KB | hring 2x128KB | rh 128KB | wz 2MB | wo 256KB]
  unsigned* flags = (unsigned*)ws;
  bf16_t*   hring = (bf16_t*)(ws + 4096);
  bf16_t*   rh_bf = (bf16_t*)(ws + 4096 + 2 * HBUF * sizeof(bf16_t));
  bf16_t*   wz_bf = (bf16_t*)(ws + 4096 + 3 * HBUF * sizeof(bf16_t));
  bf16_t*   wo_bf = (bf16_t*)(ws + 4096 + 3 * HBUF * sizeof(bf16_t)
                              + (size_t)NW * 32 * HID * sizeof(bf16_t));

  hipMemsetAsync(ws, 0, 4096, stream);

  gru_team<<<NBLK, 256, 0, stream>>>(
      X, Wr_x, Wr_h, b_r, Wz_x, Wz_h, b_z, Wh_x, Wh_h, b_h, W_o, b_o,
      (float*)d_out, hring, rh_bf, wz_bf, wo_bf, flags);
}

// Round 3
// 9405.413 us; speedup vs baseline: 1.0051x; 1.0051x over previous
//
#include <hip/hip_runtime.h>

#define HID   1024
#define TLEN  512
#define VOC   128
#define NBLK  256         // = #CUs; 1 block/CU -> all co-resident
#define NW    32          // worker team: all 32 blocks of the winner XCD
#define LDSK  1032        // padded LDS row stride
#define HBUF  (64 * HID)  // one h buffer (elements)

typedef __bf16 bf16_t;
typedef __attribute__((ext_vector_type(8))) __bf16 bf16x8;
typedef __attribute__((ext_vector_type(4))) float  f32x4;

__device__ __forceinline__ float sigmoid_fast(float x) {
  return 1.0f / (1.0f + __expf(-x));
}
__device__ __forceinline__ float tanh_fast(float x) {
  float e = __expf(-2.0f * x);
  return (1.0f - e) / (1.0f + e);
}

union PairU { bf16_t b[2]; unsigned u; };

// L1-only invalidate: subsequent plain loads re-read the (same-XCD) L2.
__device__ __forceinline__ void l1_inv() {
  asm volatile("buffer_inv" ::: "memory");
}

__device__ __forceinline__ bf16x8 ldw(const bf16_t* p) {
  return *reinterpret_cast<const bf16x8*>(p);
}

// Pure-VALU burn: 4 independent FMA chains, no memory traffic. Used to keep
// the CU's VALU issue rate high while logically idle, so the SMU holds a
// high DPM state (measured effective clock was ~650-700 MHz: MfmaUtil 1.0%
// => ~11.8k cycles/step vs 16.5-18.6us walltime).
__device__ __forceinline__ void burn_fma(int iters) {
  float a0 = 1.0f, a1 = 1.25f, a2 = 1.5f, a3 = 1.75f;
  const float m = 1.0000001f, c = 1e-7f;
  for (int it = 0; it < iters; ++it) {
    a0 = __builtin_fmaf(a0, m, c);
    a1 = __builtin_fmaf(a1, m, c);
    a2 = __builtin_fmaf(a2, m, c);
    a3 = __builtin_fmaf(a3, m, c);
  }
  asm volatile("" :: "v"(a0), "v"(a1), "v"(a2), "v"(a3));
}

// Flag wait: poll the 32 per-producer epoch words (one 128B L2 line) with
// an L1-inv'd plain load; BURN FMA between polls instead of sleeping, so the
// worker XCD's CUs stay "busy" in the SMU's eyes during the wait.
__device__ __forceinline__ void wait_flags(const unsigned* f, unsigned tgt) {
  const volatile unsigned* p =
      (const volatile unsigned*)(f + (threadIdx.x & 31));
  for (;;) {
    l1_inv();
    unsigned v = *p;
    if (__all((int)(v - tgt) >= 0)) break;   // wrap-safe compare
    burn_fma(32);                            // ~128 FMAs ≈ 0.1-0.2us granularity
  }
}

// publish: __syncthreads drains this block's stores into L2 (each wave does
// s_waitcnt vmcnt(0) before s_barrier), then one plain store of the epoch.
__device__ __forceinline__ void publish(unsigned* fw, unsigned v) {
  __syncthreads();
  if (threadIdx.x == 0) *(volatile unsigned*)fw = v;
}

#define MFMA(a, b, c) __builtin_amdgcn_mfma_f32_16x16x32_bf16((a), (b), (c), 0, 0, 0)

__global__ void __launch_bounds__(256, 1)
gru_team(const int* __restrict__ X,
         const float* __restrict__ Wr_x, const float* __restrict__ Wr_h, const float* __restrict__ b_r,
         const float* __restrict__ Wz_x, const float* __restrict__ Wz_h, const float* __restrict__ b_z,
         const float* __restrict__ Wh_x, const float* __restrict__ Wh_h, const float* __restrict__ b_h,
         const float* __restrict__ W_o,  const float* __restrict__ b_o,
         float* __restrict__ out,
         bf16_t* __restrict__ hring, bf16_t* __restrict__ rh_bf,
         bf16_t* __restrict__ wz_bf, bf16_t* __restrict__ wo_bf,
         unsigned* __restrict__ flags)
{
  __shared__ __align__(16) bf16_t Wbuf[2 * 32 * LDSK];  // Wr + Wh slices, 129KB
  __shared__ __align__(16) float  Obuf[8][16][16];      // out staging, 8KB
  __shared__ int s_role;

  unsigned* fH     = flags;        // words [0,32): h-epoch per producer block
  unsigned* fR     = flags + 32;   // words [32,64): rh-epoch per producer
  unsigned* cnt    = flags + 128;  // per-XCD claim counters (MALL atomics)
  unsigned* winner = flags + 160;  // 0 = unset, else xcd+1
  unsigned* ready  = flags + 168;  // one-time team barrier (MALL atomics)
  unsigned* done   = flags + 172;  // spinners exit when nonzero (MALL)

  const int tid  = threadIdx.x;
  const int lane = tid & 63;
  const int wv   = tid >> 6;
  const int n16  = lane & 15;
  const int q    = lane >> 4;
  const int aoff = (wv * 16 + n16) * HID + q * 8;

  int bi[4];
#pragma unroll
  for (int i = 0; i < 4; ++i) bi[i] = wv * 16 + q * 4 + i;

  // ---------- self-organize: first XCD to seat 32 blocks = worker team ------
  if (tid == 0) {
    unsigned xcc;
    asm volatile("s_getreg_b32 %0, hwreg(HW_REG_XCC_ID)" : "=s"(xcc));
    xcc &= 7u;
    unsigned idx = __hip_atomic_fetch_add(&cnt[xcc], 1u, __ATOMIC_RELAXED, __HIP_MEMORY_SCOPE_AGENT);
    if (idx == NW - 1) {
      unsigned exp = 0u;
      __hip_atomic_compare_exchange_strong(winner, &exp, xcc + 1u,
          __ATOMIC_RELAXED, __ATOMIC_RELAXED, __HIP_MEMORY_SCOPE_AGENT);
    }
    unsigned w;
    do {
      w = __hip_atomic_load(winner, __ATOMIC_RELAXED, __HIP_MEMORY_SCOPE_AGENT);
      __builtin_amdgcn_s_sleep(1);
    } while (w == 0u);
    s_role = (xcc == w - 1u && idx < NW) ? (int)idx : -1;
  }
  __syncthreads();
  const int role = s_role;

  if (role < 0) {
    // ============ clock-keepers, v2: ~99% VALU duty =========================
    // Pure-FMA burn with a realtime-gated MALL poll of `done` only every
    // ~50us (224 CUs -> ~4.5 polls/us chip-wide: negligible fabric load).
    // 60ms safety cap guarantees retirement even if `done` is missed.
    __shared__ volatile int sdone;
    if (tid == 0) sdone = 0;
    __syncthreads();
    const unsigned long long t0  = __builtin_amdgcn_s_memrealtime(); // 100MHz
    unsigned long long next      = t0 + 2000;      // first check ~20us in
    const unsigned long long cap = t0 + 6000000ull; // 60ms
    while (!sdone) {
      burn_fma(2048);    // ~8192 FMA issues ≈ 7us at full clock, no memory
      if (tid == 0) {
        unsigned long long now = __builtin_amdgcn_s_memrealtime();
        if (now >= next) {
          next = now + 5000;   // 50us between MALL polls
          if (now >= cap ||
              __hip_atomic_load(done, __ATOMIC_RELAXED,
                                __HIP_MEMORY_SCOPE_AGENT) != 0u)
            sdone = 1;
        }
      }
    }
    return;
  }

  const int s  = role;
  const int c0 = s * 32;

  // Reset my epoch words in this XCD's L2 (replay-safety; ordered before any
  // poll by the ready-barrier below).
  if (tid == 0) {
    *(volatile unsigned*)&fH[s] = 0u;
    *(volatile unsigned*)&fR[s] = 0u;
  }

  // ---------- staging: Wr/Wh -> LDS, Wz slice -> L2, W_o slice -> L2 --------
  for (int idx = tid; idx < 32 * HID; idx += 256) {
    int n = idx & 31, k = idx >> 5;
    int r = (n & 1) * 16 + (n >> 1);
    Wbuf[r * LDSK + k]             = (bf16_t)Wr_h[k * HID + c0 + n];
    Wbuf[32 * LDSK + r * LDSK + k] = (bf16_t)Wh_h[k * HID + c0 + n];
  }
  bf16_t* wzs = wz_bf + s * (32 * 1024);
  for (int idx = tid; idx < 32 * HID; idx += 256) {
    int n = idx & 31, k = idx >> 5;
    int r = (n & 1) * 16 + (n >> 1);
    wzs[r * 1024 + k] = (bf16_t)Wz_h[k * HID + c0 + n];
  }
  if (s < 8) {
    bf16_t* wos = wo_bf + s * (16 * 1024);
    for (int idx = tid; idx < 16 * HID; idx += 256) {
      int n = idx & 15, k = idx >> 4;
      wos[n * 1024 + k] = (bf16_t)W_o[k * VOC + s * 16 + n];
    }
  }
  const int j0 = c0 + 2 * n16;
#pragma unroll
  for (int i = 0; i < 4; ++i) {
    PairU zz; zz.b[0] = (bf16_t)0.f; zz.b[1] = (bf16_t)0.f;
    *reinterpret_cast<PairU*>(hring + bi[i] * HID + j0) = zz;   // h_0 = 0
  }
  __syncthreads();   // drains flag-zeroes + staging + h0

  // one-time team-wide MALL barrier
  if (tid == 0) {
    __hip_atomic_fetch_add(ready, 1u, __ATOMIC_RELAXED, __HIP_MEMORY_SCOPE_AGENT);
    while (__hip_atomic_load(ready, __ATOMIC_RELAXED, __HIP_MEMORY_SCOPE_AGENT) < NW)
      __builtin_amdgcn_s_sleep(1);
  }
  __syncthreads();
  if (tid == 0) *(volatile unsigned*)&fH[s] = 1u;   // h slot 0 ready

  // ---------- per-step constants ----------
  const float br0 = b_r[j0], br1 = b_r[j0 + 1];
  const float bz0 = b_z[j0], bz1 = b_z[j0 + 1];
  const float bh0 = b_h[j0], bh1 = b_h[j0 + 1];
  const bf16_t* wr0 = &Wbuf[n16 * LDSK + q * 8];
  const bf16_t* wr1 = &Wbuf[(16 + n16) * LDSK + q * 8];
  const bf16_t* wh0 = &Wbuf[32 * LDSK + n16 * LDSK + q * 8];
  const bf16_t* wh1 = &Wbuf[32 * LDSK + (16 + n16) * LDSK + q * 8];
  const bf16_t* wz0 = wzs + n16 * 1024 + q * 8;
  const bf16_t* wz1 = wzs + (16 + n16) * 1024 + q * 8;
  const bf16_t* rhrow = rh_bf + aoff;

  // out tile ownership: block s -> (row-tile rt, vocab-tile vt); wave rt holds
  // exactly rows rt*16..rt*16+15 of h in its areg.
  const int rt = s >> 3, vt = s & 7;
  const bool outw = (wv == rt);
  const bf16_t* wop = wo_bf + vt * (16 * 1024) + n16 * 1024 + q * 8;
  const float bo = b_o[vt * 16 + n16];

  f32x4 hm0 = {0.f,0.f,0.f,0.f}, hm1 = {0.f,0.f,0.f,0.f};  // fp32 h master

  for (int t = 0; t < TLEN; ++t) {
    // x-gather prefetch (hides under the hop-A poll)
    float gr0[4], gr1[4], gz0[4], gz1[4], gh0[4], gh1[4];
#pragma unroll
    for (int i = 0; i < 4; ++i) {
      int xb = X[bi[i] * TLEN + t];
      gr0[i] = Wr_x[xb * HID + j0]; gr1[i] = Wr_x[xb * HID + j0 + 1];
      gz0[i] = Wz_x[xb * HID + j0]; gz1[i] = Wz_x[xb * HID + j0 + 1];
      gh0[i] = Wh_x[xb * HID + j0]; gh1[i] = Wh_x[xb * HID + j0 + 1];
    }

    // ---- hop A: h_t ready ----
    wait_flags(fH, (unsigned)(t + 1));
    const bf16_t* hrow = hring + (t & 1) * HBUF + aoff;
    bf16x8 areg[32];
#pragma unroll
    for (int kk = 0; kk < 32; ++kk) areg[kk] = ldw(hrow + kk * 32);

    // ---- r phase (critical; 4 independent MFMA chains) ----
    f32x4 aR0 = {0.f,0.f,0.f,0.f}, aR1 = {0.f,0.f,0.f,0.f};
    f32x4 bR0 = {0.f,0.f,0.f,0.f}, bR1 = {0.f,0.f,0.f,0.f};
#pragma unroll
    for (int kk = 0; kk < 16; ++kk) {
      aR0 = MFMA(areg[kk],      ldw(wr0 + kk * 32),        aR0);
      aR1 = MFMA(areg[kk],      ldw(wr1 + kk * 32),        aR1);
      bR0 = MFMA(areg[kk + 16], ldw(wr0 + (kk + 16) * 32), bR0);
      bR1 = MFMA(areg[kk + 16], ldw(wr1 + (kk + 16) * 32), bR1);
    }
    aR0 += bR0; aR1 += bR1;
#pragma unroll
    for (int i = 0; i < 4; ++i) {
      float r0 = sigmoid_fast(aR0[i] + br0 + gr0[i]);
      float r1 = sigmoid_fast(aR1[i] + br1 + gr1[i]);
      PairU c;
      c.b[0] = (bf16_t)(r0 * hm0[i]);   // fp32 register master (== h_t)
      c.b[1] = (bf16_t)(r1 * hm1[i]);
      *reinterpret_cast<PairU*>(rh_bf + bi[i] * HID + j0) = c;  // local L2
    }
    publish(&fR[s], (unsigned)(t + 1));

    // ---- out[t-1] = h_t @ W_o (shadow; stores batched via LDS) ----
    if (outw && t) {
      f32x4 oa = {0.f,0.f,0.f,0.f}, ob2 = {0.f,0.f,0.f,0.f};
#pragma unroll
      for (int kk = 0; kk < 16; ++kk) {
        oa  = MFMA(areg[kk],      ldw(wop + kk * 32),        oa);
        ob2 = MFMA(areg[kk + 16], ldw(wop + (kk + 16) * 32), ob2);
      }
      oa += ob2;
      const int oi = (t - 1) & 7;
#pragma unroll
      for (int i = 0; i < 4; ++i) Obuf[oi][q * 4 + i][n16] = oa[i] + bo;
      if (oi == 7) {
        const int rb = t - 8;  // out rows rb..rb+7
#pragma unroll
        for (int k = 0; k < 8; ++k)
#pragma unroll
          for (int i = 0; i < 4; ++i)
            out[(bi[i] * TLEN + rb + k) * VOC + vt * 16 + n16] =
                Obuf[k][q * 4 + i][n16];
      }
    }

    // ---- z phase (shadow; reuses areg, streams wz from local L2) ----
    f32x4 aZ0 = {0.f,0.f,0.f,0.f}, aZ1 = {0.f,0.f,0.f,0.f};
    f32x4 bZ0 = {0.f,0.f,0.f,0.f}, bZ1 = {0.f,0.f,0.f,0.f};
#pragma unroll
    for (int kk = 0; kk < 16; ++kk) {
      aZ0 = MFMA(areg[kk],      ldw(wz0 + kk * 32),        aZ0);
      aZ1 = MFMA(areg[kk],      ldw(wz1 + kk * 32),        aZ1);
      bZ0 = MFMA(areg[kk + 16], ldw(wz0 + (kk + 16) * 32), bZ0);
      bZ1 = MFMA(areg[kk + 16], ldw(wz1 + (kk + 16) * 32), bZ1);
    }
    aZ0 += bZ0; aZ1 += bZ1;
    f32x4 z0, z1;
#pragma unroll
    for (int i = 0; i < 4; ++i) {
      z0[i] = sigmoid_fast(aZ0[i] + bz0 + gz0[i]);
      z1[i] = sigmoid_fast(aZ1[i] + bz1 + gz1[i]);
    }

    // ---- hop B: rh ready; h_tilde phase (critical) ----
    wait_flags(fR, (unsigned)(t + 1));
    l1_inv();
    bf16x8 breg[32];
#pragma unroll
    for (int kk = 0; kk < 32; ++kk) breg[kk] = ldw(rhrow + kk * 32);
    f32x4 aH0 = {0.f,0.f,0.f,0.f}, aH1 = {0.f,0.f,0.f,0.f};
    f32x4 bH0 = {0.f,0.f,0.f,0.f}, bH1 = {0.f,0.f,0.f,0.f};
#pragma unroll
    for (int kk = 0; kk < 16; ++kk) {
      aH0 = MFMA(breg[kk],      ldw(wh0 + kk * 32),        aH0);
      aH1 = MFMA(breg[kk],      ldw(wh1 + kk * 32),        aH1);
      bH0 = MFMA(breg[kk + 16], ldw(wh0 + (kk + 16) * 32), bH0);
      bH1 = MFMA(breg[kk + 16], ldw(wh1 + (kk + 16) * 32), bH1);
    }
    aH0 += bH0; aH1 += bH1;
    bf16_t* hnext = hring + ((t + 1) & 1) * HBUF;
#pragma unroll
    for (int i = 0; i < 4; ++i) {
      float ht0 = tanh_fast(aH0[i] + bh0 + gh0[i]);
      float ht1 = tanh_fast(aH1[i] + bh1 + gh1[i]);
      float hn0 = z0[i] * hm0[i] + (1.f - z0[i]) * ht0;
      float hn1 = z1[i] * hm1[i] + (1.f - z1[i]) * ht1;
      hm0[i] = hn0; hm1[i] = hn1;
      PairU c; c.b[0] = (bf16_t)hn0; c.b[1] = (bf16_t)hn1;
      *reinterpret_cast<PairU*>(hnext + bi[i] * HID + j0) = c;  // local L2
    }
    publish(&fH[s], (unsigned)(t + 2));
  }

  // ---- epilogue: out[TLEN-1] = h_TLEN @ W_o, flush rows 504..511 ----
  if (outw) {
    wait_flags(fH, (unsigned)(TLEN + 1));
    l1_inv();
    const bf16_t* hrow = hring + (TLEN & 1) * HBUF + aoff;
    bf16x8 areg[32];
#pragma unroll
    for (int kk = 0; kk < 32; ++kk) areg[kk] = ldw(hrow + kk * 32);
    f32x4 oa = {0.f,0.f,0.f,0.f}, ob2 = {0.f,0.f,0.f,0.f};
#pragma unroll
    for (int kk = 0; kk < 16; ++kk) {
      oa  = MFMA(areg[kk],      ldw(wop + kk * 32),        oa);
      ob2 = MFMA(areg[kk + 16], ldw(wop + (kk + 16) * 32), ob2);
    }
    oa += ob2;
#pragma unroll
    for (int i = 0; i < 4; ++i) Obuf[7][q * 4 + i][n16] = oa[i] + bo;
#pragma unroll
    for (int k = 0; k < 8; ++k)
#pragma unroll
      for (int i = 0; i < 4; ++i)
        out[(bi[i] * TLEN + 504 + k) * VOC + vt * 16 + n16] =
            Obuf[k][q * 4 + i][n16];
  }

  // release dirty state, then signal spinners to retire
  __builtin_amdgcn_fence(__ATOMIC_RELEASE, "agent");
  if (s == 0 && tid == 0)
    __hip_atomic_store(done, 1u, __ATOMIC_RELAXED, __HIP_MEMORY_SCOPE_AGENT);
}

extern "C" void kernel_launch(void* const* d_in, const int* in_sizes, int n_in,
                              void* d_out, int out_size, void* d_ws, size_t ws_size,
                              hipStream_t stream) {
  const int*   X    = (const int*)d_in[0];
  const float* Wr_x = (const float*)d_in[1];
  const float* Wr_h = (const float*)d_in[2];
  const float* b_r  = (const float*)d_in[3];
  const float* Wz_x = (const float*)d_in[4];
  const float* Wz_h = (const float*)d_in[5];
  const float* b_z  = (const float*)d_in[6];
  const float* Wh_x = (const float*)d_in[7];
  const float* Wh_h = (const float*)d_in[8];
  const float* b_h  = (const float*)d_in[9];
  const float* W_o  = (const float*)d_in[10];
  const float* b_o  = (const float*)d_in[11];

  char* ws = (char*)d_ws;
  // layout: [flags 4KB | hring 2x128KB | rh 128KB | wz 2MB | wo 256KB]
  unsigned* flags = (unsigned*)ws;
  bf16_t*   hring = (bf16_t*)(ws + 4096);
  bf16_t*   rh_bf = (bf16_t*)(ws + 4096 + 2 * HBUF * sizeof(bf16_t));
  bf16_t*   wz_bf = (bf16_t*)(ws + 4096 + 3 * HBUF * sizeof(bf16_t));
  bf16_t*   wo_bf = (bf16_t*)(ws + 4096 + 3 * HBUF * sizeof(bf16_t)
                              + (size_t)NW * 32 * HID * sizeof(bf16_t));

  hipMemsetAsync(ws, 0, 4096, stream);

  gru_team<<<NBLK, 256, 0, stream>>>(
      X, Wr_x, Wr_h, b_r, Wz_x, Wz_h, b_z, Wh_x, Wh_h, b_h, W_o, b_o,
      (float*)d_out, hring, rh_bf, wz_bf, wo_bf, flags);
}

// Round 4
// 7889.262 us; speedup vs baseline: 1.1982x; 1.1922x over previous
//
#include <hip/hip_runtime.h>

#define HID   1024
#define TLEN  512
#define VOC   128
#define NBLK  256         // 1 block/CU (LDS-bound) -> exactly 32 blocks/XCD
#define NT    4           // independent teams (batch-split), one per XCD
#define NB    32          // blocks per team (column-split, 32 cols each)
#define MR    16          // batch rows per team
#define LDSK  1032        // padded LDS row stride
#define HBUF  (MR * HID)  // one h buffer per team (elements)

typedef __bf16 bf16_t;
typedef __attribute__((ext_vector_type(8))) __bf16 bf16x8;
typedef __attribute__((ext_vector_type(4))) float  f32x4;

__device__ __forceinline__ float sigmoid_fast(float x) {
  return 1.0f / (1.0f + __expf(-x));
}
__device__ __forceinline__ float tanh_fast(float x) {
  float e = __expf(-2.0f * x);
  return (1.0f - e) / (1.0f + e);
}

union PairU { bf16_t b[2]; unsigned u; };

// L1-only invalidate: subsequent plain loads re-read the (same-XCD) L2.
__device__ __forceinline__ void l1_inv() {
  asm volatile("buffer_inv" ::: "memory");
}

__device__ __forceinline__ bf16x8 ldw(const bf16_t* p) {
  return *reinterpret_cast<const bf16x8*>(p);
}

// Poll the team's 32 per-producer epoch words (one 128B line in this XCD's
// L2). Busy poll, inv per iteration (plain load would otherwise re-hit a
// stale L1 line forever). 32 single-wave pollers per team line.
__device__ __forceinline__ void wait_flags(const unsigned* f, unsigned tgt) {
  const volatile unsigned* p =
      (const volatile unsigned*)(f + (threadIdx.x & 31));
  for (;;) {
    l1_inv();
    unsigned v = *p;
    if (__all((int)(v - tgt) >= 0)) break;   // wrap-safe compare
  }
}

// publish: __syncthreads makes the wave drain vmcnt(0) (stores visible in
// L2) before the single flag store.
__device__ __forceinline__ void publish(unsigned* fw, unsigned v) {
  __syncthreads();
  if (threadIdx.x == 0) *(volatile unsigned*)fw = v;
}

#define MFMA(a, b, c) __builtin_amdgcn_mfma_f32_16x16x32_bf16((a), (b), (c), 0, 0, 0)

__global__ void __launch_bounds__(64, 1)
gru_mt(const int* __restrict__ X,
       const float* __restrict__ Wr_x, const float* __restrict__ Wr_h, const float* __restrict__ b_r,
       const float* __restrict__ Wz_x, const float* __restrict__ Wz_h, const float* __restrict__ b_z,
       const float* __restrict__ Wh_x, const float* __restrict__ Wh_h, const float* __restrict__ b_h,
       const float* __restrict__ W_o,  const float* __restrict__ b_o,
       float* __restrict__ out,
       bf16_t* __restrict__ hring, bf16_t* __restrict__ rh_bf,
       bf16_t* __restrict__ wz_bf, bf16_t* __restrict__ wo_bf,
       unsigned* __restrict__ flags)
{
  __shared__ __align__(16) bf16_t Wbuf[2 * 32 * LDSK];  // Wr + Wh slices, 129KB
  __shared__ __align__(16) float  Obuf[8][16][16];      // out staging, 8KB
  __shared__ int s_team, s_slot;

  // flag-space layout (words; first 16KB of ws is memset to 0 each launch):
  //   team t: fH = flags + 256t (+0..31), fR = fH + 64
  //   cnt[x]   at 1024 + 32x   (per-XCD claim counters, MALL atomics)
  //   tcnt     at 1536         (team claim counter)
  //   xteam[x] at 2048 + 32x   (0=unset, k+1=team k, 0xFF=loser XCD)
  //   ready    at 3072         (one-time global barrier, 128 arrivals)
  unsigned* cnt   = flags + 1024;
  unsigned* tcnt  = flags + 1536;
  unsigned* xteam = flags + 2048;
  unsigned* ready = flags + 3072;

  const int tid  = threadIdx.x;
  const int n16  = tid & 15;
  const int q    = tid >> 4;

  int bi[4];
#pragma unroll
  for (int i = 0; i < 4; ++i) bi[i] = q * 4 + i;   // local batch rows 0..15

  // ---------- self-organize: every XCD seats exactly 32 blocks (1/CU, 256
  // blocks, 32 CU/XCD). The 32nd block claims a team id; first NT XCDs win.
  if (tid == 0) {
    unsigned xcc;
    asm volatile("s_getreg_b32 %0, hwreg(HW_REG_XCC_ID)" : "=s"(xcc));
    xcc &= 7u;
    unsigned idx = __hip_atomic_fetch_add(&cnt[xcc * 32], 1u,
        __ATOMIC_RELAXED, __HIP_MEMORY_SCOPE_AGENT);
    if (idx == NB - 1) {
      unsigned tcl = __hip_atomic_fetch_add(tcnt, 1u,
          __ATOMIC_RELAXED, __HIP_MEMORY_SCOPE_AGENT);
      __hip_atomic_store(&xteam[xcc * 32], (tcl < NT) ? (tcl + 1u) : 0xFFu,
          __ATOMIC_RELAXED, __HIP_MEMORY_SCOPE_AGENT);
    }
    unsigned v;
    do {
      v = __hip_atomic_load(&xteam[xcc * 32], __ATOMIC_RELAXED,
                            __HIP_MEMORY_SCOPE_AGENT);
      __builtin_amdgcn_s_sleep(1);
    } while (v == 0u);
    s_team = (v == 0xFFu) ? -1 : (int)(v - 1u);
    s_slot = (int)idx;
  }
  __syncthreads();
  const int tau = s_team;
  if (tau < 0) return;                 // losing XCDs exit (no spinners)
  const int s  = s_slot;               // 0..31: column slice owner
  const int c0 = s * 32;

  unsigned* fH = flags + tau * 256;
  unsigned* fR = fH + 64;

  // Re-zero my epoch words in THIS XCD's L2 (replay safety; visible before
  // any poll via the drain at the ready barrier below).
  if (tid == 0) {
    *(volatile unsigned*)&fH[s] = 0u;
    *(volatile unsigned*)&fR[s] = 0u;
  }

  // ---------- staging ----------
  // Wr/Wh column slices -> LDS (per block; interleaved-pair permutation)
  for (int idx = tid; idx < 32 * HID; idx += 64) {
    int n = idx & 31, k = idx >> 5;
    int r = (n & 1) * 16 + (n >> 1);
    Wbuf[r * LDSK + k]             = (bf16_t)Wr_h[k * HID + c0 + n];
    Wbuf[32 * LDSK + r * LDSK + k] = (bf16_t)Wh_h[k * HID + c0 + n];
  }
  // Wz (bf16) and W_o (bf16) staged ONCE by team 0, shared read-only by all
  // teams (each XCD's L2 caches clean copies of the lines its team reads).
  bf16_t* wzs = wz_bf + s * (32 * HID);
  if (tau == 0) {
    for (int idx = tid; idx < 32 * HID; idx += 64) {
      int n = idx & 31, k = idx >> 5;
      int r = (n & 1) * 16 + (n >> 1);
      wzs[r * HID + k] = (bf16_t)Wz_h[k * HID + c0 + n];
    }
    if (s < 8) {
      bf16_t* wos = wo_bf + s * (16 * HID);
      for (int idx = tid; idx < 16 * HID; idx += 64) {
        int n = idx & 15, k = idx >> 4;
        wos[n * HID + k] = (bf16_t)W_o[k * VOC + s * 16 + n];
      }
    }
  }

  bf16_t* hT  = hring + tau * (2 * HBUF);
  bf16_t* rhT = rh_bf + tau * HBUF;
  const int j0 = c0 + 2 * n16;
#pragma unroll
  for (int i = 0; i < 4; ++i) {
    PairU zz; zz.b[0] = (bf16_t)0.f; zz.b[1] = (bf16_t)0.f;
    *reinterpret_cast<PairU*>(hT + bi[i] * HID + j0) = zz;   // h_0 = 0
  }
  __syncthreads();   // drains flag-zero + staging + h0 stores (vmcnt(0))

  // one-time global ready barrier (covers shared wz/wo staging too)
  if (tid == 0) {
    __hip_atomic_fetch_add(ready, 1u, __ATOMIC_RELAXED, __HIP_MEMORY_SCOPE_AGENT);
    while (__hip_atomic_load(ready, __ATOMIC_RELAXED, __HIP_MEMORY_SCOPE_AGENT)
           < (unsigned)(NT * NB))
      __builtin_amdgcn_s_sleep(1);
  }
  __syncthreads();
  if (tid == 0) *(volatile unsigned*)&fH[s] = 1u;   // h slot 0 ready

  // ---------- per-step constants ----------
  const float br0 = b_r[j0], br1 = b_r[j0 + 1];
  const float bz0 = b_z[j0], bz1 = b_z[j0 + 1];
  const float bh0 = b_h[j0], bh1 = b_h[j0 + 1];
  const bf16_t* wr0 = &Wbuf[n16 * LDSK + q * 8];
  const bf16_t* wr1 = &Wbuf[(16 + n16) * LDSK + q * 8];
  const bf16_t* wh0 = &Wbuf[32 * LDSK + n16 * LDSK + q * 8];
  const bf16_t* wh1 = &Wbuf[32 * LDSK + (16 + n16) * LDSK + q * 8];
  const bf16_t* wz0 = wzs + n16 * HID + q * 8;
  const bf16_t* wz1 = wzs + (16 + n16) * HID + q * 8;
  const int  aoff  = n16 * HID + q * 8;
  const bf16_t* rhrow = rhT + aoff;

  // out tile: block s<8 computes vocab cols [16s,16s+16) for the team's 16
  // rows, in the rh-wait shadow, reusing areg (full-K h fragment).
  const bool outw = (s < 8);
  const int  vt   = s;
  const bf16_t* wop = wo_bf + vt * (16 * HID) + n16 * HID + q * 8;
  const float bo = outw ? b_o[vt * 16 + n16] : 0.f;
  const int  gb0 = tau * MR;    // global batch row base

  f32x4 hm0 = {0.f,0.f,0.f,0.f}, hm1 = {0.f,0.f,0.f,0.f};  // fp32 h master

  for (int t = 0; t < TLEN; ++t) {
    // x-gather prefetch (hides under the hop-A poll)
    float gr0[4], gr1[4], gz0[4], gz1[4], gh0[4], gh1[4];
#pragma unroll
    for (int i = 0; i < 4; ++i) {
      int xb = X[(gb0 + bi[i]) * TLEN + t];
      gr0[i] = Wr_x[xb * HID + j0]; gr1[i] = Wr_x[xb * HID + j0 + 1];
      gz0[i] = Wz_x[xb * HID + j0]; gz1[i] = Wz_x[xb * HID + j0 + 1];
      gh0[i] = Wh_x[xb * HID + j0]; gh1[i] = Wh_x[xb * HID + j0 + 1];
    }

    // ---- hop A: h_t ready ----
    wait_flags(fH, (unsigned)(t + 1));
    const bf16_t* hrow = hT + (t & 1) * HBUF + aoff;
    bf16x8 areg[32];
#pragma unroll
    for (int kk = 0; kk < 32; ++kk) areg[kk] = ldw(hrow + kk * 32);

    // ---- r phase (critical; 4 independent MFMA chains) ----
    f32x4 aR0 = {0.f,0.f,0.f,0.f}, aR1 = {0.f,0.f,0.f,0.f};
    f32x4 bR0 = {0.f,0.f,0.f,0.f}, bR1 = {0.f,0.f,0.f,0.f};
#pragma unroll
    for (int kk = 0; kk < 16; ++kk) {
      aR0 = MFMA(areg[kk],      ldw(wr0 + kk * 32),        aR0);
      aR1 = MFMA(areg[kk],      ldw(wr1 + kk * 32),        aR1);
      bR0 = MFMA(areg[kk + 16], ldw(wr0 + (kk + 16) * 32), bR0);
      bR1 = MFMA(areg[kk + 16], ldw(wr1 + (kk + 16) * 32), bR1);
    }
    aR0 += bR0; aR1 += bR1;
#pragma unroll
    for (int i = 0; i < 4; ++i) {
      float r0 = sigmoid_fast(aR0[i] + br0 + gr0[i]);
      float r1 = sigmoid_fast(aR1[i] + br1 + gr1[i]);
      PairU c;
      c.b[0] = (bf16_t)(r0 * hm0[i]);   // fp32 register master (== h_t)
      c.b[1] = (bf16_t)(r1 * hm1[i]);
      *reinterpret_cast<PairU*>(rhT + bi[i] * HID + j0) = c;
    }
    publish(&fR[s], (unsigned)(t + 1));

    // ---- out[t-1] = h_t @ W_o (shadow; stores batched via LDS) ----
    if (outw && t) {
      f32x4 oa = {0.f,0.f,0.f,0.f}, ob2 = {0.f,0.f,0.f,0.f};
#pragma unroll
      for (int kk = 0; kk < 16; ++kk) {
        oa  = MFMA(areg[kk],      ldw(wop + kk * 32),        oa);
        ob2 = MFMA(areg[kk + 16], ldw(wop + (kk + 16) * 32), ob2);
      }
      oa += ob2;
      const int oi = (t - 1) & 7;
#pragma unroll
      for (int i = 0; i < 4; ++i) Obuf[oi][bi[i]][n16] = oa[i] + bo;
      if (oi == 7) {
        const int rb = t - 8;  // flush out rows rb..rb+7
#pragma unroll
        for (int m = 0; m < 32; ++m) {
          int e = m * 64 + tid;
          int row = e >> 7, tt = (e >> 4) & 7, cc = e & 15;
          out[((gb0 + row) * TLEN + rb + tt) * VOC + vt * 16 + cc] =
              Obuf[tt][row][cc];
        }
      }
    }

    // ---- z phase (shadow; reuses areg, streams wz from local L2) ----
    f32x4 aZ0 = {0.f,0.f,0.f,0.f}, aZ1 = {0.f,0.f,0.f,0.f};
    f32x4 bZ0 = {0.f,0.f,0.f,0.f}, bZ1 = {0.f,0.f,0.f,0.f};
#pragma unroll
    for (int kk = 0; kk < 16; ++kk) {
      aZ0 = MFMA(areg[kk],      ldw(wz0 + kk * 32),        aZ0);
      aZ1 = MFMA(areg[kk],      ldw(wz1 + kk * 32),        aZ1);
      bZ0 = MFMA(areg[kk + 16], ldw(wz0 + (kk + 16) * 32), bZ0);
      bZ1 = MFMA(areg[kk + 16], ldw(wz1 + (kk + 16) * 32), bZ1);
    }
    aZ0 += bZ0; aZ1 += bZ1;
    f32x4 z0, z1;
#pragma unroll
    for (int i = 0; i < 4; ++i) {
      z0[i] = sigmoid_fast(aZ0[i] + bz0 + gz0[i]);
      z1[i] = sigmoid_fast(aZ1[i] + bz1 + gz1[i]);
    }

    // ---- hop B: rh ready; h_tilde phase (critical) ----
    wait_flags(fR, (unsigned)(t + 1));
    bf16x8 breg[32];
#pragma unroll
    for (int kk = 0; kk < 32; ++kk) breg[kk] = ldw(rhrow + kk * 32);
    f32x4 aH0 = {0.f,0.f,0.f,0.f}, aH1 = {0.f,0.f,0.f,0.f};
    f32x4 bH0 = {0.f,0.f,0.f,0.f}, bH1 = {0.f,0.f,0.f,0.f};
#pragma unroll
    for (int kk = 0; kk < 16; ++kk) {
      aH0 = MFMA(breg[kk],      ldw(wh0 + kk * 32),        aH0);
      aH1 = MFMA(breg[kk],      ldw(wh1 + kk * 32),        aH1);
      bH0 = MFMA(breg[kk + 16], ldw(wh0 + (kk + 16) * 32), bH0);
      bH1 = MFMA(breg[kk + 16], ldw(wh1 + (kk + 16) * 32), bH1);
    }
    aH0 += bH0; aH1 += bH1;
    bf16_t* hnext = hT + ((t + 1) & 1) * HBUF;
#pragma unroll
    for (int i = 0; i < 4; ++i) {
      float ht0 = tanh_fast(aH0[i] + bh0 + gh0[i]);
      float ht1 = tanh_fast(aH1[i] + bh1 + gh1[i]);
      float hn0 = z0[i] * hm0[i] + (1.f - z0[i]) * ht0;
      float hn1 = z1[i] * hm1[i] + (1.f - z1[i]) * ht1;
      hm0[i] = hn0; hm1[i] = hn1;
      PairU c; c.b[0] = (bf16_t)hn0; c.b[1] = (bf16_t)hn1;
      *reinterpret_cast<PairU*>(hnext + bi[i] * HID + j0) = c;
    }
    publish(&fH[s], (unsigned)(t + 2));
  }

  // ---- epilogue: out[TLEN-1] = h_TLEN @ W_o, flush rows 504..511 ----
  if (outw) {
    wait_flags(fH, (unsigned)(TLEN + 1));
    const bf16_t* hrow = hT + (TLEN & 1) * HBUF + aoff;
    bf16x8 areg[32];
#pragma unroll
    for (int kk = 0; kk < 32; ++kk) areg[kk] = ldw(hrow + kk * 32);
    f32x4 oa = {0.f,0.f,0.f,0.f}, ob2 = {0.f,0.f,0.f,0.f};
#pragma unroll
    for (int kk = 0; kk < 16; ++kk) {
      oa  = MFMA(areg[kk],      ldw(wop + kk * 32),        oa);
      ob2 = MFMA(areg[kk + 16], ldw(wop + (kk + 16) * 32), ob2);
    }
    oa += ob2;
#pragma unroll
    for (int i = 0; i < 4; ++i) Obuf[7][bi[i]][n16] = oa[i] + bo;
#pragma unroll
    for (int m = 0; m < 32; ++m) {
      int e = m * 64 + tid;
      int row = e >> 7, tt = (e >> 4) & 7, cc = e & 15;
      out[((gb0 + row) * TLEN + 504 + tt) * VOC + vt * 16 + cc] =
          Obuf[tt][row][cc];
    }
  }

  // write back/order dirty state for the next replay
  __builtin_amdgcn_fence(__ATOMIC_RELEASE, "agent");
}

extern "C" void kernel_launch(void* const* d_in, const int* in_sizes, int n_in,
                              void* d_out, int out_size, void* d_ws, size_t ws_size,
                              hipStream_t stream) {
  const int*   X    = (const int*)d_in[0];
  const float* Wr_x = (const float*)d_in[1];
  const float* Wr_h = (const float*)d_in[2];
  const float* b_r  = (const float*)d_in[3];
  const float* Wz_x = (const float*)d_in[4];
  const float* Wz_h = (const float*)d_in[5];
  const float* b_z  = (const float*)d_in[6];
  const float* Wh_x = (const float*)d_in[7];
  const float* Wh_h = (const float*)d_in[8];
  const float* b_h  = (const float*)d_in[9];
  const float* W_o  = (const float*)d_in[10];
  const float* b_o  = (const float*)d_in[11];

  char* ws = (char*)d_ws;
  // layout: [flags 16KB | hring 4x2x32KB | rh 4x32KB | wz 2MB | wo 256KB]
  unsigned* flags = (unsigned*)ws;
  bf16_t*   hring = (bf16_t*)(ws + 16384);
  bf16_t*   rh_bf = (bf16_t*)(ws + 16384 + (size_t)NT * 2 * HBUF * sizeof(bf16_t));
  bf16_t*   wz_bf = (bf16_t*)(ws + 16384 + (size_t)NT * 3 * HBUF * sizeof(bf16_t));
  bf16_t*   wo_bf = (bf16_t*)(ws + 16384 + (size_t)NT * 3 * HBUF * sizeof(bf16_t)
                              + (size_t)NB * 32 * HID * sizeof(bf16_t));

  hipMemsetAsync(ws, 0, 16384, stream);

  gru_mt<<<NBLK, 64, 0, stream>>>(
      X, Wr_x, Wr_h, b_r, Wz_x, Wz_h, b_z, Wh_x, Wh_h, b_h, W_o, b_o,
      (float*)d_out, hring, rh_bf, wz_bf, wo_bf, flags);
}